// Round 7
// baseline (520.686 us; speedup 1.0000x reference)
//
#include <hip/hip_runtime.h>

// Problem constants (fixed by reference)
#define BB 4
#define NN 4096

// INSTRUMENTATION ROUND: every kernel runs its body TWICE (idempotent).
// dur_us - 430.28 == total kernel time K; any kernel with 2x-dur > ~157us
// surfaces in the fill-flooded top-5 WITH counters. Revert next round.
#define REPS 2

typedef __attribute__((ext_vector_type(8))) short short8;
typedef __attribute__((ext_vector_type(4))) float f32x4;

__device__ __forceinline__ unsigned short f2bf(float f) {
    union { float f; unsigned int i; } cv; cv.f = f;
    unsigned int i = cv.i;
    return (unsigned short)((i + 0x7FFFu + ((i >> 16) & 1u)) >> 16);
}
__device__ __forceinline__ float asf(unsigned int u) {
    union { unsigned int i; float f; } cv; cv.i = u; return cv.f;
}

// ---------------------------------------------------------------------------
// Kernel A: fold weights (blocks 0-127, t<128) + pack adj -> bitmask (all).
// pack: purely linear 268 MB read, 16 independent float4 loads in flight/wave,
// 1024 blocks (4/CU). bitT[b][s][g*4+j] u64: bit l <-> col g*256 + 4l + j
// ---------------------------------------------------------------------------
__global__ __launch_bounds__(256) void kA(const float* __restrict__ adj,
                                          const float* __restrict__ Wmsg,
                                          const float* __restrict__ Wupd,
                                          unsigned short* __restrict__ WcatT,
                                          unsigned long long* __restrict__ bitT) {
    __shared__ float fS[128], fR[128];
    int bid = blockIdx.x, t = threadIdx.x;
    if (bid < 128) {   // fold: WcatT[n][k]; n 0:128 Wu_top^T, 128:256 Wr@Wu_bot, 256:384 Ws@Wu_bot
        int k = bid;
        if (t < 128) { fS[t] = Wmsg[k * 128 + t]; fR[t] = Wmsg[(128 + k) * 128 + t]; }
        __syncthreads();
        if (t < 128) {
            float a1 = 0.f, a2 = 0.f;
#pragma unroll 8
            for (int m = 0; m < 128; ++m) {
                float wu = Wupd[(128 + m) * 128 + t];
                a1 += fS[m] * wu;
                a2 += fR[m] * wu;
            }
            WcatT[(size_t)t * 128 + k]         = f2bf(Wupd[k * 128 + t]);
            WcatT[(size_t)(128 + t) * 128 + k] = f2bf(a2);
            WcatT[(size_t)(256 + t) * 128 + k] = f2bf(a1);
        }
    }
    // pack: block = 16 full rows of one batch
    int b  = bid >> 8;
    int s0 = (bid & 255) * 16;
    int wv = t >> 6, l = t & 63;      // wave covers cols [wv*1024, +1024)
    const float* ab = adj + ((size_t)b * NN + s0) * NN + wv * 1024 + l * 4;
    unsigned long long* bt = bitT + ((size_t)(b * NN + s0) << 6);
#pragma unroll 1
    for (int rep = 0; rep < REPS; ++rep) {
        asm volatile("" ::: "memory");     // block cross-rep load CSE / dead-store elim
        for (int i = 0; i < 16; i += 4) {
            float4 v0[4], v1[4], v2[4], v3[4];   // 16 loads issued back-to-back
#pragma unroll
            for (int it = 0; it < 4; ++it) {
                v0[it] = *(const float4*)(ab + (size_t)(i + 0) * NN + it * 256);
                v1[it] = *(const float4*)(ab + (size_t)(i + 1) * NN + it * 256);
                v2[it] = *(const float4*)(ab + (size_t)(i + 2) * NN + it * 256);
                v3[it] = *(const float4*)(ab + (size_t)(i + 3) * NN + it * 256);
            }
#pragma unroll
            for (int u = 0; u < 4; ++u) {
                float4* v = (u == 0) ? v0 : (u == 1) ? v1 : (u == 2) ? v2 : v3;
                int row = i + u;
#pragma unroll
                for (int it = 0; it < 4; ++it) {
                    unsigned long long m0 = __ballot(v[it].x != 0.0f);
                    unsigned long long m1 = __ballot(v[it].y != 0.0f);
                    unsigned long long m2 = __ballot(v[it].z != 0.0f);
                    unsigned long long m3 = __ballot(v[it].w != 0.0f);
                    if (l < 4) {
                        unsigned long long wd = (l == 0) ? m0 : (l == 1) ? m1 : (l == 2) ? m2 : m3;
                        bt[((size_t)row << 6) + (wv * 4 + it) * 4 + l] = wd;
                    }
                }
            }
        }
    }
}

// ---------------------------------------------------------------------------
// Kernel B: [T1|D2|YB] = x @ Wcat (16384x128 @ 128x384), NO LDS staging.
// 768 blocks: 256 m-tiles x 3 n-blocks.
// ---------------------------------------------------------------------------
__global__ __launch_bounds__(256) void kB(const float* __restrict__ X,
                                          const unsigned short* __restrict__ WcatT,
                                          float* __restrict__ TD,
                                          unsigned short* __restrict__ YB) {
    int bid = blockIdx.x, t = threadIdx.x;
    int m0 = (bid & 255) * 64;
    int nb = bid >> 8;                // 0,1 -> TD; 2 -> YB
    int lane = t & 63, wave = t >> 6;
    int quad = lane >> 4, lr = lane & 15;
    const float* xr = X + (size_t)(m0 + wave * 16 + lr) * 128;
    const unsigned short* wbase = WcatT + ((size_t)nb << 14) + (size_t)lr * 128 + quad * 8;

#pragma unroll 1
    for (int rep = 0; rep < REPS; ++rep) {
        asm volatile("" ::: "memory");
        auto LOADA = [&](int KK) -> short8 {
            float4 f0 = *(const float4*)(xr + KK * 32 + quad * 8);
            float4 f1 = *(const float4*)(xr + KK * 32 + quad * 8 + 4);
            short8 av;
            av[0] = (short)f2bf(f0.x); av[1] = (short)f2bf(f0.y);
            av[2] = (short)f2bf(f0.z); av[3] = (short)f2bf(f0.w);
            av[4] = (short)f2bf(f1.x); av[5] = (short)f2bf(f1.y);
            av[6] = (short)f2bf(f1.z); av[7] = (short)f2bf(f1.w);
            return av;
        };
        short8 a0 = LOADA(0), a1 = LOADA(1), a2 = LOADA(2), a3 = LOADA(3);

        f32x4 acc[8];
#pragma unroll
        for (int s = 0; s < 8; ++s) acc[s] = (f32x4)0.f;

#pragma unroll
        for (int kk = 0; kk < 4; ++kk) {
            short8 a = (kk == 0) ? a0 : (kk == 1) ? a1 : (kk == 2) ? a2 : a3;
#pragma unroll
            for (int s = 0; s < 8; ++s) {
                short8 bf = *(const short8*)(wbase + (size_t)(s * 16) * 128 + kk * 32);
                acc[s] = __builtin_amdgcn_mfma_f32_16x16x32_bf16(a, bf, acc[s], 0, 0, 0);
            }
        }
        // epilogue: C/D mapping col = lane&15, row = quad*4 + reg  [m89/m91]
        if (nb == 2) {
#pragma unroll
            for (int s = 0; s < 8; ++s)
#pragma unroll
                for (int r = 0; r < 4; ++r) {
                    int row = m0 + wave * 16 + quad * 4 + r;
                    YB[(size_t)row * 128 + s * 16 + lr] = f2bf(acc[s][r]);
                }
        } else {
#pragma unroll
            for (int s = 0; s < 8; ++s)
#pragma unroll
                for (int r = 0; r < 4; ++r) {
                    int row = m0 + wave * 16 + quad * 4 + r;
                    TD[(size_t)row * 256 + nb * 128 + s * 16 + lr] = acc[s][r];
                }
        }
    }
}

// ---------------------------------------------------------------------------
// Kernel C: 16 receivers/block. Build edge lists from the L2-resident bitmask
// (nibble ffs loops, work ~ #edges), then per-receiver wave gather of ys rows
// (256 B coalesced L2 reads/edge) + fused epilogue.
// ---------------------------------------------------------------------------
__global__ __launch_bounds__(256) void kC(const unsigned long long* __restrict__ bitT,
                                          const unsigned int* __restrict__ YB32,
                                          const float* __restrict__ TD,
                                          float* __restrict__ out) {
    __shared__ int cnt[16];
    __shared__ unsigned short list[16][128];   // P(Binom(4096,.01) > 128) ~ 1e-26
    int bid  = blockIdx.x, t = threadIdx.x;
    int b    = bid >> 8;
    int rg16 = bid & 255;                      // receiver group: cols rg16*16..+16
    int g  = rg16 >> 4;                        // 256-col group in bitT
    int l0 = (rg16 & 15) * 4;                  // ballot-lane base: col = g*256+4l+j
    const unsigned long long* bt = bitT + ((size_t)(b * NN) << 6) + (g << 2);
    int lane = t & 63, w = t >> 6;
    const unsigned int* yb = YB32 + ((size_t)b << 18) + lane;   // u32 = 2 bf16 ch

#pragma unroll 1
    for (int rep = 0; rep < REPS; ++rep) {
        asm volatile("" ::: "memory");
        if (t < 16) cnt[t] = 0;
        __syncthreads();

        for (int i = 0; i < NN / 256; ++i) {
            int s = t + 256 * i;
            const unsigned long long* p = bt + ((size_t)s << 6);
            unsigned long long w0 = p[0], w1 = p[1], w2 = p[2], w3 = p[3];
            unsigned n0 = (unsigned)(w0 >> l0) & 0xFu;   // local col c = 4*bit + j
            unsigned n1 = (unsigned)(w1 >> l0) & 0xFu;
            unsigned n2 = (unsigned)(w2 >> l0) & 0xFu;
            unsigned n3 = (unsigned)(w3 >> l0) & 0xFu;
            while (n0) { int i2 = __ffs(n0) - 1; n0 &= n0 - 1; int c = 4 * i2;     int sl = atomicAdd(&cnt[c], 1); if (sl < 128) list[c][sl] = (unsigned short)s; }
            while (n1) { int i2 = __ffs(n1) - 1; n1 &= n1 - 1; int c = 4 * i2 + 1; int sl = atomicAdd(&cnt[c], 1); if (sl < 128) list[c][sl] = (unsigned short)s; }
            while (n2) { int i2 = __ffs(n2) - 1; n2 &= n2 - 1; int c = 4 * i2 + 2; int sl = atomicAdd(&cnt[c], 1); if (sl < 128) list[c][sl] = (unsigned short)s; }
            while (n3) { int i2 = __ffs(n3) - 1; n3 &= n3 - 1; int c = 4 * i2 + 3; int sl = atomicAdd(&cnt[c], 1); if (sl < 128) list[c][sl] = (unsigned short)s; }
        }
        __syncthreads();

        for (int q = 0; q < 4; ++q) {
            int c   = w * 4 + q;
            int rgl = b * NN + rg16 * 16 + c;
            int deg = cnt[c];
            int ctot = min(deg, 128);
            const float2* td = (const float2*)(TD + (size_t)rgl * 256);
            float2 t1 = td[lane];
            float2 res = t1;
            if (deg > 0) {
                float al0 = 0.f, ah0 = 0.f, al1 = 0.f, ah1 = 0.f;
                float al2 = 0.f, ah2 = 0.f, al3 = 0.f, ah3 = 0.f;
                const unsigned short* ls = list[c];
                int e = 0;
                for (; e + 4 <= ctot; e += 4) {                    // 4-deep L2 MLP
                    int s0 = ls[e], s1 = ls[e + 1], s2 = ls[e + 2], s3 = ls[e + 3];
                    unsigned u0 = yb[(size_t)s0 << 6];
                    unsigned u1 = yb[(size_t)s1 << 6];
                    unsigned u2 = yb[(size_t)s2 << 6];
                    unsigned u3 = yb[(size_t)s3 << 6];
                    al0 += asf(u0 << 16); ah0 += asf(u0 & 0xffff0000u);
                    al1 += asf(u1 << 16); ah1 += asf(u1 & 0xffff0000u);
                    al2 += asf(u2 << 16); ah2 += asf(u2 & 0xffff0000u);
                    al3 += asf(u3 << 16); ah3 += asf(u3 & 0xffff0000u);
                }
                for (; e < ctot; ++e) {
                    unsigned u = yb[(size_t)ls[e] << 6];
                    al0 += asf(u << 16); ah0 += asf(u & 0xffff0000u);
                }
                float inv = 1.0f / (float)deg;
                float2 d2 = td[64 + lane];
                res.x = t1.x + d2.x + (al0 + al1 + al2 + al3) * inv;
                res.y = t1.y + d2.y + (ah0 + ah1 + ah2 + ah3) * inv;
            }
            ((float2*)(out + (size_t)rgl * 128))[lane] = res;
        }
        __syncthreads();   // keep reps cleanly separated (cnt reinit next rep)
    }
}

// ---------------------------------------------------------------------------
extern "C" void kernel_launch(void* const* d_in, const int* in_sizes, int n_in,
                              void* d_out, int out_size, void* d_ws, size_t ws_size,
                              hipStream_t stream) {
    const float* x    = (const float*)d_in[0];   // 16384 x 128
    const float* adj  = (const float*)d_in[1];   // 4 x 4096 x 4096
    const float* Wmsg = (const float*)d_in[2];   // 256 x 128
    const float* Wupd = (const float*)d_in[3];   // 256 x 128
    float* out = (float*)d_out;                  // 16384 x 128

    // workspace (bytes): WcatT 128K | TD 16M | YB 4M (row-major [b*4096+s][n]) | bitT 8M
    char* ws = (char*)d_ws;
    unsigned short*     WcatT = (unsigned short*)(ws);
    float*              TD    = (float*)(ws + 131072);
    unsigned short*     YB    = (unsigned short*)(ws + 131072 + 16777216);
    unsigned long long* bitT  = (unsigned long long*)(ws + 131072 + 16777216 + 4194304);

    kA<<<1024, 256, 0, stream>>>(adj, Wmsg, Wupd, WcatT, bitT);
    kB<<<768, 256, 0, stream>>>(x, WcatT, TD, YB);
    kC<<<1024, 256, 0, stream>>>(bitT, (const unsigned int*)YB, TD, out);
}

// Round 8
// 413.306 us; speedup vs baseline: 1.2598x; 1.2598x over previous
//
#include <hip/hip_runtime.h>

// Problem constants (fixed by reference)
#define BB 4
#define NN 4096

// R7 attribution result: total kernel time = 90.4 us (doubling experiment);
// ~340 us of the 430 is fixed harness overhead (2x 1-GiB poison fills + launch).
// This round: eliminate TD round-trip (fuse into kC), g-major bitT for
// coalesced kC scan, kB -> YB-only.

typedef __attribute__((ext_vector_type(8))) short short8;
typedef __attribute__((ext_vector_type(4))) float f32x4;

__device__ __forceinline__ unsigned short f2bf(float f) {
    union { float f; unsigned int i; } cv; cv.f = f;
    unsigned int i = cv.i;
    return (unsigned short)((i + 0x7FFFu + ((i >> 16) & 1u)) >> 16);
}
__device__ __forceinline__ float asf(unsigned int u) {
    union { unsigned int i; float f; } cv; cv.i = u; return cv.f;
}

// ---------------------------------------------------------------------------
// Kernel A: fold weights (blocks 0-127, t<128) + pack adj -> bitmask (all).
// pack: purely linear 268 MB read, 16 independent float4 loads in flight/wave,
// 1024 blocks (4/CU).
// bitT layout (g-major, NEW): bitT[((b*16 + g)*NN + s)*4 + j], g = col/256,
// word j: bit l <-> col g*256 + 4l + j. A kC block's slice (fixed g) is a
// contiguous 128 KB stream (was 32 B @ 512 B stride).
// ---------------------------------------------------------------------------
__global__ __launch_bounds__(256) void kA(const float* __restrict__ adj,
                                          const float* __restrict__ Wmsg,
                                          const float* __restrict__ Wupd,
                                          unsigned short* __restrict__ WcatT,
                                          unsigned long long* __restrict__ bitT) {
    __shared__ float fS[128], fR[128];
    int bid = blockIdx.x, t = threadIdx.x;
    if (bid < 128) {   // fold: WcatT[n][k]; n 0:128 Wu_top^T, 128:256 Wr@Wu_bot, 256:384 Ws@Wu_bot
        int k = bid;
        if (t < 128) { fS[t] = Wmsg[k * 128 + t]; fR[t] = Wmsg[(128 + k) * 128 + t]; }
        __syncthreads();
        if (t < 128) {
            float a1 = 0.f, a2 = 0.f;
#pragma unroll 8
            for (int m = 0; m < 128; ++m) {
                float wu = Wupd[(128 + m) * 128 + t];
                a1 += fS[m] * wu;
                a2 += fR[m] * wu;
            }
            WcatT[(size_t)t * 128 + k]         = f2bf(Wupd[k * 128 + t]);
            WcatT[(size_t)(128 + t) * 128 + k] = f2bf(a2);
            WcatT[(size_t)(256 + t) * 128 + k] = f2bf(a1);
        }
    }
    // pack: block = 16 full rows of one batch
    int b  = bid >> 8;
    int s0 = (bid & 255) * 16;
    int wv = t >> 6, l = t & 63;      // wave covers cols [wv*1024, +1024)
    const float* ab = adj + ((size_t)b * NN + s0) * NN + wv * 1024 + l * 4;
    unsigned long long* btb = bitT + ((size_t)(b * 16)) * NN * 4;
    for (int i = 0; i < 16; i += 4) {
        float4 v0[4], v1[4], v2[4], v3[4];   // 16 loads issued back-to-back
#pragma unroll
        for (int it = 0; it < 4; ++it) {
            v0[it] = *(const float4*)(ab + (size_t)(i + 0) * NN + it * 256);
            v1[it] = *(const float4*)(ab + (size_t)(i + 1) * NN + it * 256);
            v2[it] = *(const float4*)(ab + (size_t)(i + 2) * NN + it * 256);
            v3[it] = *(const float4*)(ab + (size_t)(i + 3) * NN + it * 256);
        }
#pragma unroll
        for (int u = 0; u < 4; ++u) {
            float4* v = (u == 0) ? v0 : (u == 1) ? v1 : (u == 2) ? v2 : v3;  // const-folded
            int s = s0 + i + u;
#pragma unroll
            for (int it = 0; it < 4; ++it) {
                unsigned long long m0 = __ballot(v[it].x != 0.0f);
                unsigned long long m1 = __ballot(v[it].y != 0.0f);
                unsigned long long m2 = __ballot(v[it].z != 0.0f);
                unsigned long long m3 = __ballot(v[it].w != 0.0f);
                if (l < 4) {
                    unsigned long long wd = (l == 0) ? m0 : (l == 1) ? m1 : (l == 2) ? m2 : m3;
                    int g = wv * 4 + it;
                    btb[((size_t)g * NN + s) * 4 + l] = wd;   // 32 B contiguous per group
                }
            }
        }
    }
}

// ---------------------------------------------------------------------------
// Kernel B: YB = bf16( x @ (Ws@Wu_bot) ), row-major [b*4096+s][128]. 256 blocks.
// A: f32->bf16 in-register from L3-resident X. B: direct from L2-resident WcatT.
// ---------------------------------------------------------------------------
__global__ __launch_bounds__(256) void kB(const float* __restrict__ X,
                                          const unsigned short* __restrict__ WcatT,
                                          unsigned short* __restrict__ YB) {
    int bid = blockIdx.x, t = threadIdx.x;
    int m0 = bid * 64;
    int lane = t & 63, wave = t >> 6;
    int quad = lane >> 4, lr = lane & 15;
    const float* xr = X + (size_t)(m0 + wave * 16 + lr) * 128;
    const unsigned short* wbase = WcatT + ((size_t)2 << 14) + (size_t)lr * 128 + quad * 8;

    auto LOADA = [&](int KK) -> short8 {
        float4 f0 = *(const float4*)(xr + KK * 32 + quad * 8);
        float4 f1 = *(const float4*)(xr + KK * 32 + quad * 8 + 4);
        short8 av;
        av[0] = (short)f2bf(f0.x); av[1] = (short)f2bf(f0.y);
        av[2] = (short)f2bf(f0.z); av[3] = (short)f2bf(f0.w);
        av[4] = (short)f2bf(f1.x); av[5] = (short)f2bf(f1.y);
        av[6] = (short)f2bf(f1.z); av[7] = (short)f2bf(f1.w);
        return av;
    };
    short8 a0 = LOADA(0), a1 = LOADA(1), a2 = LOADA(2), a3 = LOADA(3);

    f32x4 acc[8];
#pragma unroll
    for (int s = 0; s < 8; ++s) acc[s] = (f32x4)0.f;
#pragma unroll
    for (int kk = 0; kk < 4; ++kk) {
        short8 a = (kk == 0) ? a0 : (kk == 1) ? a1 : (kk == 2) ? a2 : a3;
#pragma unroll
        for (int s = 0; s < 8; ++s) {
            short8 bf = *(const short8*)(wbase + (size_t)(s * 16) * 128 + kk * 32);
            acc[s] = __builtin_amdgcn_mfma_f32_16x16x32_bf16(a, bf, acc[s], 0, 0, 0);
        }
    }
    // C/D mapping col = lane&15, row = quad*4 + reg  [m89/m91]
#pragma unroll
    for (int s = 0; s < 8; ++s)
#pragma unroll
        for (int r = 0; r < 4; ++r) {
            int row = m0 + wave * 16 + quad * 4 + r;
            YB[(size_t)row * 128 + s * 16 + lr] = f2bf(acc[s][r]);
        }
}

// ---------------------------------------------------------------------------
// Kernel C: 16 receivers/block, fully fused:
//  (1) build edge lists from g-major bitmask (coalesced 2 KB/wave-instr reads)
//  (2) compute this block's TD tile in-register: [16 rows x 256 n] = x@Wcat
//      (T1|D2) via MFMA -> LDS (TD never touches HBM)
//  (3) per-receiver wave gather of ys rows + epilogue from LDS.
// ---------------------------------------------------------------------------
__global__ __launch_bounds__(256) void kC(const float* __restrict__ X,
                                          const unsigned short* __restrict__ WcatT,
                                          const unsigned long long* __restrict__ bitT,
                                          const unsigned int* __restrict__ YB32,
                                          float* __restrict__ out) {
    __shared__ int cnt[16];
    __shared__ unsigned short list[16][128];   // P(Binom(4096,.01) > 128) ~ 1e-26
    __shared__ float TDl[16][256];             // 16 KB: block's T1|D2 tile
    int bid  = blockIdx.x, t = threadIdx.x;
    int b    = bid >> 8;
    int rg16 = bid & 255;                      // receiver group: cols rg16*16..+16
    int g  = rg16 >> 4;                        // 256-col group in bitT
    int l0 = (rg16 & 15) * 4;                  // ballot-lane base: col = g*256+4l+j
    if (t < 16) cnt[t] = 0;
    __syncthreads();

    // (1) scan: g-major layout -> contiguous stream
    {
        const unsigned long long* bt = bitT + ((size_t)(b * 16 + g)) * NN * 4;
        for (int i = 0; i < NN / 256; ++i) {
            int s = t + 256 * i;
            const unsigned long long* p = bt + ((size_t)s << 2);
            unsigned long long w0 = p[0], w1 = p[1], w2 = p[2], w3 = p[3];
            unsigned n0 = (unsigned)(w0 >> l0) & 0xFu;   // local col c = 4*bit + j
            unsigned n1 = (unsigned)(w1 >> l0) & 0xFu;
            unsigned n2 = (unsigned)(w2 >> l0) & 0xFu;
            unsigned n3 = (unsigned)(w3 >> l0) & 0xFu;
            while (n0) { int i2 = __ffs(n0) - 1; n0 &= n0 - 1; int c = 4 * i2;     int sl = atomicAdd(&cnt[c], 1); if (sl < 128) list[c][sl] = (unsigned short)s; }
            while (n1) { int i2 = __ffs(n1) - 1; n1 &= n1 - 1; int c = 4 * i2 + 1; int sl = atomicAdd(&cnt[c], 1); if (sl < 128) list[c][sl] = (unsigned short)s; }
            while (n2) { int i2 = __ffs(n2) - 1; n2 &= n2 - 1; int c = 4 * i2 + 2; int sl = atomicAdd(&cnt[c], 1); if (sl < 128) list[c][sl] = (unsigned short)s; }
            while (n3) { int i2 = __ffs(n3) - 1; n3 &= n3 - 1; int c = 4 * i2 + 3; int sl = atomicAdd(&cnt[c], 1); if (sl < 128) list[c][sl] = (unsigned short)s; }
        }
    }

    // (2) TD tile: 16 rows (this block's receivers) x 256 n. Wave w owns
    // n-range [w*64, w*64+64). A-rows shared across waves (L3-resident X).
    int lane = t & 63, w = t >> 6;
    int quad = lane >> 4, lr = lane & 15;
    {
        int rrow0 = b * NN + rg16 * 16;
        const float* xr = X + (size_t)(rrow0 + lr) * 128;
        auto LOADA = [&](int KK) -> short8 {
            float4 f0 = *(const float4*)(xr + KK * 32 + quad * 8);
            float4 f1 = *(const float4*)(xr + KK * 32 + quad * 8 + 4);
            short8 av;
            av[0] = (short)f2bf(f0.x); av[1] = (short)f2bf(f0.y);
            av[2] = (short)f2bf(f0.z); av[3] = (short)f2bf(f0.w);
            av[4] = (short)f2bf(f1.x); av[5] = (short)f2bf(f1.y);
            av[6] = (short)f2bf(f1.z); av[7] = (short)f2bf(f1.w);
            return av;
        };
        short8 a0 = LOADA(0), a1 = LOADA(1), a2 = LOADA(2), a3 = LOADA(3);
        f32x4 acc[4];
#pragma unroll
        for (int s = 0; s < 4; ++s) acc[s] = (f32x4)0.f;
        const unsigned short* wbase = WcatT + (size_t)(w * 64 + lr) * 128 + quad * 8;
#pragma unroll
        for (int kk = 0; kk < 4; ++kk) {
            short8 a = (kk == 0) ? a0 : (kk == 1) ? a1 : (kk == 2) ? a2 : a3;
#pragma unroll
            for (int s = 0; s < 4; ++s) {
                short8 bf = *(const short8*)(wbase + (size_t)(s * 16) * 128 + kk * 32);
                acc[s] = __builtin_amdgcn_mfma_f32_16x16x32_bf16(a, bf, acc[s], 0, 0, 0);
            }
        }
        // C/D: row(m) = quad*4+r (receiver), col(n) = w*64 + s*16 + lr
#pragma unroll
        for (int s = 0; s < 4; ++s)
#pragma unroll
            for (int r = 0; r < 4; ++r)
                TDl[quad * 4 + r][w * 64 + s * 16 + lr] = acc[s][r];
    }
    __syncthreads();

    // (3) gather + epilogue (T1/D2 from LDS)
    const unsigned int* yb = YB32 + ((size_t)b << 18) + lane;   // u32 = 2 bf16 ch
    for (int q = 0; q < 4; ++q) {
        int c   = w * 4 + q;
        int rgl = b * NN + rg16 * 16 + c;
        int deg = cnt[c];
        int ctot = min(deg, 128);
        float2 t1 = *(const float2*)&TDl[c][2 * lane];
        float2 res = t1;
        if (deg > 0) {
            float al0 = 0.f, ah0 = 0.f, al1 = 0.f, ah1 = 0.f;
            float al2 = 0.f, ah2 = 0.f, al3 = 0.f, ah3 = 0.f;
            const unsigned short* ls = list[c];
            int e = 0;
            for (; e + 4 <= ctot; e += 4) {                    // 4-deep L2 MLP
                int s0 = ls[e], s1 = ls[e + 1], s2 = ls[e + 2], s3 = ls[e + 3];
                unsigned u0 = yb[(size_t)s0 << 6];
                unsigned u1 = yb[(size_t)s1 << 6];
                unsigned u2 = yb[(size_t)s2 << 6];
                unsigned u3 = yb[(size_t)s3 << 6];
                al0 += asf(u0 << 16); ah0 += asf(u0 & 0xffff0000u);
                al1 += asf(u1 << 16); ah1 += asf(u1 & 0xffff0000u);
                al2 += asf(u2 << 16); ah2 += asf(u2 & 0xffff0000u);
                al3 += asf(u3 << 16); ah3 += asf(u3 & 0xffff0000u);
            }
            for (; e < ctot; ++e) {
                unsigned u = yb[(size_t)ls[e] << 6];
                al0 += asf(u << 16); ah0 += asf(u & 0xffff0000u);
            }
            float inv = 1.0f / (float)deg;
            float2 d2 = *(const float2*)&TDl[c][128 + 2 * lane];
            res.x = t1.x + d2.x + (al0 + al1 + al2 + al3) * inv;
            res.y = t1.y + d2.y + (ah0 + ah1 + ah2 + ah3) * inv;
        }
        ((float2*)(out + (size_t)rgl * 128))[lane] = res;
    }
}

// ---------------------------------------------------------------------------
extern "C" void kernel_launch(void* const* d_in, const int* in_sizes, int n_in,
                              void* d_out, int out_size, void* d_ws, size_t ws_size,
                              hipStream_t stream) {
    const float* x    = (const float*)d_in[0];   // 16384 x 128
    const float* adj  = (const float*)d_in[1];   // 4 x 4096 x 4096
    const float* Wmsg = (const float*)d_in[2];   // 256 x 128
    const float* Wupd = (const float*)d_in[3];   // 256 x 128
    float* out = (float*)d_out;                  // 16384 x 128

    // workspace (bytes): WcatT 128K | YB 4M (row-major [b*4096+s][n]) | bitT 8M (g-major)
    char* ws = (char*)d_ws;
    unsigned short*     WcatT = (unsigned short*)(ws);
    unsigned short*     YB    = (unsigned short*)(ws + 131072);
    unsigned long long* bitT  = (unsigned long long*)(ws + 131072 + 4194304);

    kA<<<1024, 256, 0, stream>>>(adj, Wmsg, Wupd, WcatT, bitT);
    kB<<<256, 256, 0, stream>>>(x, WcatT, YB);
    kC<<<1024, 256, 0, stream>>>(x, WcatT, bitT, (const unsigned int*)YB, out);
}